// Round 2
// baseline (893.715 us; speedup 1.0000x reference)
//
#include <hip/hip_runtime.h>

// ---------------------------------------------------------------------------
// MultiDimensionalLSTM on MI355X.
// B=32, C=32, Y=X=128, win 4x4 -> grid 32x32 cells, F=512, R=128, gates 5R=640.
// Wavefront over 63 anti-diagonals. Input projection hoisted to one MFMA GEMM.
// PRECISION: split-bf16 (hi+lo) everywhere -> fp32-quality gates via 3-term
// MFMA (ah*bh + ah*bl + al*bh); c-state fp32; h carried as bf16 hi+lo pair.
// ---------------------------------------------------------------------------

typedef unsigned short u16;
typedef __attribute__((ext_vector_type(8))) short short8;     // 8 bf16 (4 VGPRs)
typedef __attribute__((ext_vector_type(8))) unsigned short us8;
typedef __attribute__((ext_vector_type(4))) float floatx4;

__device__ inline u16 f2bf(float f) {               // RNE fp32 -> bf16
  unsigned u = __float_as_uint(f);
  u += 0x7fffu + ((u >> 16) & 1u);
  return (u16)(u >> 16);
}
__device__ inline float bf2f(u16 v) { return __uint_as_float(((unsigned)v) << 16); }

__device__ inline void async16(u16* lds, const u16* g) {
  // dest = wave-uniform base + lane*16 (caller must arrange this)
  __builtin_amdgcn_global_load_lds((const __attribute__((address_space(1))) void*)g,
                                   (__attribute__((address_space(3))) void*)lds, 16, 0, 0);
}

__device__ inline float sigf(float x) { return 1.f / (1.f + __expf(-x)); }
__device__ inline float tanh_fast(float x) { return 1.f - 2.f / (__expf(2.f * x) + 1.f); }

// ---------------------------------------------------------------------------
// Prep 1: W [768][640] fp32 -> WxT_{h,l} [640 pcol][512 k], WhT_{h,l} [640][256],
// biasp [640]. pcol = r*5+g  <->  orig col g*128+r (gate-interleaved).
// WhT row k: k<128 -> W row 512+k (up h1), k>=128 -> W row 640+(k-128) (left h2).
// ---------------------------------------------------------------------------
__global__ __launch_bounds__(256) void k_wprep(const float* __restrict__ W,
                                               const float* __restrict__ bias,
                                               u16* __restrict__ WxT_h, u16* __restrict__ WxT_l,
                                               u16* __restrict__ WhT_h, u16* __restrict__ WhT_l,
                                               float* __restrict__ biasp) {
  int pcol = blockIdx.x;                       // 0..639
  int col  = (pcol % 5) * 128 + pcol / 5;      // original gate column
  for (int k = threadIdx.x; k < 768; k += 256) {
    float v = W[(size_t)k * 640 + col];
    u16 hi = f2bf(v);
    u16 lo = f2bf(v - bf2f(hi));
    if (k < 512) { WxT_h[(size_t)pcol * 512 + k] = hi; WxT_l[(size_t)pcol * 512 + k] = lo; }
    else { WhT_h[(size_t)pcol * 256 + (k - 512)] = hi; WhT_l[(size_t)pcol * 256 + (k - 512)] = lo; }
  }
  if (threadIdx.x == 0) biasp[pcol] = bias[col];
}

// ---------------------------------------------------------------------------
// Prep 2: gather x [B,C,Y,X] -> xs hi/lo [t=0..1023][b=0..31][f=0..511].
// xs[t][b][f] = x[b][f&31][t>>3][(t&7)*16 + (f>>5)]
// ---------------------------------------------------------------------------
__global__ __launch_bounds__(256) void k_xgather(const float* __restrict__ x,
                                                 u16* __restrict__ xs_h,
                                                 u16* __restrict__ xs_l) {
  int lane = threadIdx.x & 63;
  int pair = blockIdx.x * 4 + (threadIdx.x >> 6);  // 0..32767 == t*32+b
  int t = pair >> 5, b = pair & 31;
  int y = t >> 3, x0 = (t & 7) * 16;
  int j = lane >> 2;                // f>>5, 0..15
  int cbase = (lane & 3) * 8;       // f&31 base
  const float* src = x + ((size_t)b * 32 * 128 + y) * 128 + x0 + j;
  us8 vh, vl;
#pragma unroll
  for (int u = 0; u < 8; ++u) {
    float f = src[(size_t)(cbase + u) * 16384];
    u16 hi = f2bf(f);
    vh[u] = hi;
    vl[u] = f2bf(f - bf2f(hi));
  }
  *(us8*)(xs_h + (size_t)pair * 512 + lane * 8) = vh;
  *(us8*)(xs_l + (size_t)pair * 512 + lane * 8) = vl;
}

// ---------------------------------------------------------------------------
// Input GEMM (split-bf16): G[m][pcol] = biasp + sum_k xs[m][k]*WxT[pcol][k]
// M=32768, N=640, K=512. 128x128 tile, BK=32, 4 waves, 4x4 16x16x32 acc/wave.
// ---------------------------------------------------------------------------
__global__ __launch_bounds__(256) void k_gemm_in(const u16* __restrict__ xs_h,
                                                 const u16* __restrict__ xs_l,
                                                 const u16* __restrict__ WxT_h,
                                                 const u16* __restrict__ WxT_l,
                                                 const float* __restrict__ biasp,
                                                 float* __restrict__ Gp) {
  __shared__ u16 Ah[128 * 32], Al[128 * 32];   // [m][k], 8 KB each
  __shared__ u16 Bh[128 * 32], Bl[128 * 32];   // [n][k]
  const int tid = threadIdx.x;
  const int wv = tid >> 6, lane = tid & 63;
  const int quad = lane >> 4, l16 = lane & 15;
  const int m0 = blockIdx.x * 128;
  const int n0 = blockIdx.y * 128;
  const int arow = lane >> 2;            // row within 16-row chunk
  const int acol = (lane & 3) * 8;       // u16 offset within 64B row

  floatx4 acc[4][4] = {};

  for (int kt = 0; kt < 512; kt += 32) {
#pragma unroll
    for (int i = 0; i < 2; ++i) {
      int chunk = wv * 2 + i;            // 0..7, 16 rows each
      int row = chunk * 16 + arow;
      size_t aoff = (size_t)(m0 + row) * 512 + kt + acol;
      size_t boff = (size_t)(n0 + row) * 512 + kt + acol;
      async16(&Ah[chunk * 512 + lane * 8], xs_h + aoff);
      async16(&Al[chunk * 512 + lane * 8], xs_l + aoff);
      async16(&Bh[chunk * 512 + lane * 8], WxT_h + boff);
      async16(&Bl[chunk * 512 + lane * 8], WxT_l + boff);
    }
    __syncthreads();
    short8 afh[4], afl[4], bfh[4], bfl[4];
#pragma unroll
    for (int mt = 0; mt < 4; ++mt) {
      int ro = ((wv & 1) * 64 + mt * 16 + l16) * 32 + quad * 8;
      afh[mt] = *(const short8*)&Ah[ro];
      afl[mt] = *(const short8*)&Al[ro];
    }
#pragma unroll
    for (int nt = 0; nt < 4; ++nt) {
      int ro = ((wv >> 1) * 64 + nt * 16 + l16) * 32 + quad * 8;
      bfh[nt] = *(const short8*)&Bh[ro];
      bfl[nt] = *(const short8*)&Bl[ro];
    }
#pragma unroll
    for (int mt = 0; mt < 4; ++mt)
#pragma unroll
      for (int nt = 0; nt < 4; ++nt) {
        floatx4 a = acc[mt][nt];
        a = __builtin_amdgcn_mfma_f32_16x16x32_bf16(afl[mt], bfh[nt], a, 0, 0, 0);
        a = __builtin_amdgcn_mfma_f32_16x16x32_bf16(afh[mt], bfl[nt], a, 0, 0, 0);
        a = __builtin_amdgcn_mfma_f32_16x16x32_bf16(afh[mt], bfh[nt], a, 0, 0, 0);
        acc[mt][nt] = a;
      }
    __syncthreads();
  }
#pragma unroll
  for (int nt = 0; nt < 4; ++nt) {
    int n = n0 + (wv >> 1) * 64 + nt * 16 + l16;
    float bv = biasp[n];
#pragma unroll
    for (int mt = 0; mt < 4; ++mt) {
      int m = m0 + (wv & 1) * 64 + mt * 16 + quad * 4;
#pragma unroll
      for (int r = 0; r < 4; ++r)
        Gp[(size_t)(m + r) * 640 + n] = acc[mt][nt][r] + bv;
    }
  }
}

// ---------------------------------------------------------------------------
// Recurrent diagonal kernel. Grid (8 slices, 32 cells), block 128 (2 waves).
// Slice si owns pcols [si*80, si*80+80) == r in [si*16, si*16+16).
// A/B fragments loaded straight from global (L2-resident), no LDS staging.
// gates[32,80] = Hcat[32,256] @ WhT_slice^T + Gp ; nonlinearity + state update.
// ---------------------------------------------------------------------------
__global__ __launch_bounds__(128) void k_diag(int d,
                                              const u16* __restrict__ WhT_h,
                                              const u16* __restrict__ WhT_l,
                                              const float* __restrict__ Gp,
                                              float* __restrict__ cbuf,
                                              u16* __restrict__ hbf_h,
                                              u16* __restrict__ hbf_l,
                                              float* __restrict__ out) {
  __shared__ float Gs[32 * 80];        // 10 KB gate shuffle buffer

  const int si = blockIdx.x;           // 0..7
  const int ci = blockIdx.y;           // 0..31
  const int hlo = max(0, d - 31);
  const int ncells = min(31, d) - hlo + 1;
  if (ci >= ncells) return;
  const int h = hlo + ci, w = d - h, t = h * 32 + w;
  const int tid = threadIdx.x;
  const int wv = tid >> 6, lane = tid & 63;
  const int quad = lane >> 4, l16 = lane & 15;
  const bool upok = (t > 32);          // faithful off-by-one: cell (1,0) gets no up
  const bool leftok = (w > 0);

  floatx4 acc[5] = {};
  const size_t bbase = (size_t)(si * 80 + l16) * 256 + quad * 8;
  const short8 z8 = {0, 0, 0, 0, 0, 0, 0, 0};

#pragma unroll
  for (int ks = 0; ks < 8; ++ks) {
    // A fragment: Hcat[b = wv*16+l16][k = ks*32 + quad*8 + j]
    // k<128 -> h_up (t-32); k>=128 -> h_left (t-1); zeros if not ok.
    const bool ok = (ks < 4) ? upok : leftok;
    const int tt = (ks < 4) ? (t - 32) : (t - 1);
    short8 ah = z8, al = z8;
    if (ok) {
      size_t aoff = ((size_t)tt * 32 + wv * 16 + l16) * 128 + (ks & 3) * 32 + quad * 8;
      ah = *(const short8*)(hbf_h + aoff);
      al = *(const short8*)(hbf_l + aoff);
    }
#pragma unroll
    for (int nt = 0; nt < 5; ++nt) {
      size_t bo = bbase + (size_t)nt * 16 * 256 + ks * 32;
      short8 bh = *(const short8*)(WhT_h + bo);
      short8 bl = *(const short8*)(WhT_l + bo);
      floatx4 a = acc[nt];
      a = __builtin_amdgcn_mfma_f32_16x16x32_bf16(al, bh, a, 0, 0, 0);
      a = __builtin_amdgcn_mfma_f32_16x16x32_bf16(ah, bl, a, 0, 0, 0);
      a = __builtin_amdgcn_mfma_f32_16x16x32_bf16(ah, bh, a, 0, 0, 0);
      acc[nt] = a;
    }
  }

  // epilogue: gates = acc + Gp -> Gs  (D: row=quad*4+r -> b, col=l16 -> n-local)
#pragma unroll
  for (int nt = 0; nt < 5; ++nt) {
    int pl = nt * 16 + l16;
#pragma unroll
    for (int r = 0; r < 4; ++r) {
      int b = wv * 16 + quad * 4 + r;
      Gs[b * 80 + pl] = acc[nt][r] + Gp[((size_t)t * 32 + b) * 640 + si * 80 + pl];
    }
  }
  __syncthreads();

  // nonlinearity + state update: 512 (b, rr) pairs; pl = rr*5 + g
#pragma unroll
  for (int u = 0; u < 4; ++u) {
    int pair = u * 128 + tid;
    int b = pair >> 4, rr = pair & 15;
    int r = si * 16 + rr;
    const float* gp = &Gs[b * 80 + rr * 5];
    float gi = gp[0], gj = gp[1], g1 = gp[2], g2 = gp[3], go = gp[4];
    float c1 = upok   ? cbuf[((size_t)(t - 32) * 32 + b) * 128 + r] : 0.f;
    float c2 = leftok ? cbuf[((size_t)(t - 1) * 32 + b) * 128 + r] : 0.f;
    float nc_ = c1 * sigf(g1) + c2 * sigf(g2) + sigf(gi) * tanh_fast(gj);
    float nh  = tanh_fast(nc_) * sigf(go);
    cbuf[((size_t)t * 32 + b) * 128 + r] = nc_;
    u16 hh = f2bf(nh);
    hbf_h[((size_t)t * 32 + b) * 128 + r] = hh;
    hbf_l[((size_t)t * 32 + b) * 128 + r] = f2bf(nh - bf2f(hh));
    out[(((size_t)b * 32 + h) * 32 + w) * 128 + r] = nh;   // [B,H,W,R]
  }
}

// ---------------------------------------------------------------------------
extern "C" void kernel_launch(void* const* d_in, const int* in_sizes, int n_in,
                              void* d_out, int out_size, void* d_ws, size_t ws_size,
                              hipStream_t stream) {
  const float* x    = (const float*)d_in[0];   // [32,32,128,128]
  const float* W    = (const float*)d_in[1];   // [768,640]
  const float* bias = (const float*)d_in[2];   // [640]
  float* out = (float*)d_out;                  // [32,32,32,128]
  char* ws = (char*)d_ws;

  size_t off = 0;
  u16*   xs_h  = (u16*)(ws + off);  off += (size_t)32768 * 512 * 2;  // 33.6 MB
  u16*   xs_l  = (u16*)(ws + off);  off += (size_t)32768 * 512 * 2;  // 33.6 MB
  u16*   WxT_h = (u16*)(ws + off);  off += (size_t)640 * 512 * 2;
  u16*   WxT_l = (u16*)(ws + off);  off += (size_t)640 * 512 * 2;
  u16*   WhT_h = (u16*)(ws + off);  off += (size_t)640 * 256 * 2;
  u16*   WhT_l = (u16*)(ws + off);  off += (size_t)640 * 256 * 2;
  float* biasp = (float*)(ws + off); off += (size_t)640 * 4;
  float* Gp    = (float*)(ws + off); off += (size_t)32768 * 640 * 4; // 83.9 MB
  float* cbuf  = (float*)(ws + off); off += (size_t)32768 * 128 * 4; // 16.8 MB
  u16*   hbf_h = (u16*)(ws + off);  off += (size_t)32768 * 128 * 2;  // 8.4 MB
  u16*   hbf_l = (u16*)(ws + off);  off += (size_t)32768 * 128 * 2;  // 8.4 MB
  (void)ws_size;

  k_wprep<<<dim3(640), dim3(256), 0, stream>>>(W, bias, WxT_h, WxT_l, WhT_h, WhT_l, biasp);
  k_xgather<<<dim3(8192), dim3(256), 0, stream>>>(x, xs_h, xs_l);
  k_gemm_in<<<dim3(256, 5), dim3(256), 0, stream>>>(xs_h, xs_l, WxT_h, WxT_l, biasp, Gp);
  for (int d = 0; d < 63; ++d)
    k_diag<<<dim3(8, 32), dim3(128), 0, stream>>>(d, WhT_h, WhT_l, Gp, cbuf, hbf_h, hbf_l, out);
}